// Round 1
// baseline (1248.086 us; speedup 1.0000x reference)
//
#include <hip/hip_runtime.h>

#define B_TOT 16384
#define T_STEPS 128
#define F_IN 29
#define K_HID 512
#define D_IN 32
#define NW 4        // waves per block (node dimension split 4 ways)
#define NTILE 8     // node tiles per wave = 512 / (16*NW)
#define XS 33       // sX row stride (floats): frag-read banks <=2-way aliased (free)

typedef __attribute__((ext_vector_type(8))) short short8;   // 8 bf16 (MFMA A/B frag)
typedef __attribute__((ext_vector_type(4))) float floatx4;  // MFMA C/D frag

__device__ __forceinline__ float fast_tanh(float x) {
    float e = __expf(2.0f * x);
    return 1.0f - 2.0f * __builtin_amdgcn_rcpf(e + 1.0f);
}
__device__ __forceinline__ short bf16_hi_bits(float x) {
    return (short)(__float_as_uint(x) >> 16);
}
__device__ __forceinline__ float bf16_hi_f(float x) {
    return __uint_as_float(__float_as_uint(x) & 0xffff0000u);
}

// 4 waves per block; each wave owns the SAME 16 batch rows but 1/4 of the 512
// hidden nodes (8 MFMA tiles, bf16x3). 1024 blocks x 4 waves = 4 waves/SIMD
// chip-wide, so one wave's tanh/W2 VALU work hides under another wave's MFMA
// and stall windows. Cross-wave W2 partial combine via LDS ping-pong; ONE
// __syncthreads per step. pred(t-1) is combined at the top of iteration t
// (feedback + output therefore lag one iteration; tail flushed after loop).
__global__ __launch_bounds__(256, 4)
void narx_wave4(const float* __restrict__ X,   // [B][T][29]
                const float* __restrict__ y0,  // [B][3]
                const float* __restrict__ W1,  // [32][512]
                const float* __restrict__ b1,  // [512]
                const float* __restrict__ W2,  // [512]
                const float* __restrict__ b2,  // [1]
                float* __restrict__ out)       // [B][T]
{
    __shared__ float sX[2][16 * XS];    // 4224 B
    __shared__ float pp[2][NW][16];     // 512 B: per-wave W2 partials per row

    const int tid  = threadIdx.x;       // 0..255
    const int wv   = tid >> 6;          // wave id 0..3
    const int lane = tid & 63;
    const int q    = lane >> 4;         // 0..3
    const int m    = lane & 15;         // batch row (A/C) and node col (B)
    const size_t row0 = (size_t)blockIdx.x * 16;

    // ---- one-time: this wave's W1 B-fragments (bf16 hi/lo), b1, W2 ----
    // wave wv owns nodes [wv*128, wv*128+128); B[k][n]: n = lane&15, k = q*8+j
    short8 whi[NTILE], wlo[NTILE];
    float b1v[NTILE], w2v[NTILE];
    #pragma unroll
    for (int nt = 0; nt < NTILE; ++nt) {
        int node = wv * (NTILE * 16) + nt * 16 + m;
        #pragma unroll
        for (int j = 0; j < 8; ++j) {
            int k = q * 8 + j;
            float v  = W1[k * K_HID + node];
            float hf = bf16_hi_f(v);
            whi[nt][j] = bf16_hi_bits(v);
            wlo[nt][j] = bf16_hi_bits(v - hf);
        }
        b1v[nt] = b1[node];
        w2v[nt] = W2[node];
    }
    const float b2v = b2[0];

    // every lane tracks fb for its own row m (identical across waves)
    float fb0 = y0[(row0 + m) * 3 + 0];
    float fb1 = y0[(row0 + m) * 3 + 1];
    float fb2 = y0[(row0 + m) * 3 + 2];

    // ---- X staging: 464 floats/step spread over 256 threads (<=2 each) ----
    const float* Xblk = X + row0 * (T_STEPS * F_IN);
    const int f0 = tid;                    // always < 464
    const int f1 = tid + 256;
    const bool v1 = (f1 < 16 * F_IN);
    const int r0 = f0 / F_IN, c0 = f0 - r0 * F_IN;
    const int r1 = f1 / F_IN, c1 = f1 - r1 * F_IN;
    const int xo0 = r0 * (T_STEPS * F_IN) + c0;
    const int xo1 = r1 * (T_STEPS * F_IN) + c1;
    const int lo0 = r0 * XS + c0;
    const int lo1 = r1 * XS + c1;

    // stage X(0)
    float xp0 = Xblk[xo0];
    float xp1 = v1 ? Xblk[xo1] : 0.f;
    sX[0][lo0] = xp0;
    if (v1) sX[0][lo1] = xp1;

    float4 pv = make_float4(0.f, 0.f, 0.f, 0.f);

    for (int t = 0; t < T_STEPS; ++t) {
        const int cur = t & 1;
        __syncthreads();   // publishes: sX[cur]=X(t), pp[cur^1]=partials(t-1)

        // ---- combine pred(t-1) across waves; feedback shift; output ----
        if (t > 0) {
            const int pb = cur ^ 1;
            float fbn = pp[pb][0][m] + pp[pb][1][m]
                      + pp[pb][2][m] + pp[pb][3][m] + b2v;
            fb2 = fb1; fb1 = fb0; fb0 = fbn;
            if (wv == 0 && m < 4) {        // lane (q, m<4) owns row q*4+m
                const int ro = q * 4 + m;
                float po = pp[pb][0][ro] + pp[pb][1][ro]
                         + pp[pb][2][ro] + pp[pb][3][ro] + b2v;
                pv = make_float4(pv.y, pv.z, pv.w, po);
                if (((t - 1) & 3) == 3)
                    *(float4*)&out[(row0 + ro) * T_STEPS + (t - 4)] = pv;
            }
        }

        // ---- A-frag: LDS reads + fb inject + bf16 hi/lo split ----
        const float* sxm = &sX[cur][m * XS];
        short8 ahi, alo;
        #pragma unroll
        for (int j = 0; j < 8; ++j) {
            float xj = sxm[q * 8 + j];
            if (q == 3 && j == 5) xj = fb0;   // k = 29
            if (q == 3 && j == 6) xj = fb1;   // k = 30
            if (q == 3 && j == 7) xj = fb2;   // k = 31
            float hf = bf16_hi_f(xj);
            ahi[j] = bf16_hi_bits(xj);
            alo[j] = bf16_hi_bits(xj - hf);
        }

        // prefetch X(t+1) into registers (drained at the ds_write below)
        const int tn = (t + 1 < T_STEPS) ? (t + 1) : t;
        xp0 = Xblk[xo0 + tn * F_IN];
        if (v1) xp1 = Xblk[xo1 + tn * F_IN];

        // ---- 8 node tiles: bf16x3 MFMA + tanh + W2 partial ----
        float pa0 = 0.f, pa1 = 0.f, pa2 = 0.f, pa3 = 0.f;
        #pragma unroll
        for (int nt = 0; nt < NTILE; ++nt) {
            floatx4 c = {b1v[nt], b1v[nt], b1v[nt], b1v[nt]};
            c = __builtin_amdgcn_mfma_f32_16x16x32_bf16(ahi, whi[nt], c, 0, 0, 0);
            c = __builtin_amdgcn_mfma_f32_16x16x32_bf16(ahi, wlo[nt], c, 0, 0, 0);
            c = __builtin_amdgcn_mfma_f32_16x16x32_bf16(alo, whi[nt], c, 0, 0, 0);
            // C/D: col(node) = lane&15, row(batch) = q*4 + reg
            pa0 = fmaf(fast_tanh(c[0]), w2v[nt], pa0);
            pa1 = fmaf(fast_tanh(c[1]), w2v[nt], pa1);
            pa2 = fmaf(fast_tanh(c[2]), w2v[nt], pa2);
            pa3 = fmaf(fast_tanh(c[3]), w2v[nt], pa3);
        }

        // ---- in-wave reduce over the 16 node cols (lane bits 0..3) ----
        #pragma unroll
        for (int mask = 1; mask <= 8; mask <<= 1) {
            pa0 += __shfl_xor(pa0, mask, 64);
            pa1 += __shfl_xor(pa1, mask, 64);
            pa2 += __shfl_xor(pa2, mask, 64);
            pa3 += __shfl_xor(pa3, mask, 64);
        }
        // pa[reg] = this wave's partial for row q*4+reg, replicated over m

        if (m == 0)
            *(float4*)&pp[cur][wv][q * 4] = make_float4(pa0, pa1, pa2, pa3);

        // ---- publish X(t+1) into the other buffer ----
        sX[cur ^ 1][lo0] = xp0;
        if (v1) sX[cur ^ 1][lo1] = xp1;
    }

    // ---- tail: combine pred(127), flush last output quad ----
    __syncthreads();
    if (wv == 0 && m < 4) {
        const int pb = (T_STEPS - 1) & 1;
        const int ro = q * 4 + m;
        float po = pp[pb][0][ro] + pp[pb][1][ro]
                 + pp[pb][2][ro] + pp[pb][3][ro] + b2v;
        pv = make_float4(pv.y, pv.z, pv.w, po);
        *(float4*)&out[(row0 + ro) * T_STEPS + (T_STEPS - 4)] = pv;
    }
}

extern "C" void kernel_launch(void* const* d_in, const int* in_sizes, int n_in,
                              void* d_out, int out_size, void* d_ws, size_t ws_size,
                              hipStream_t stream) {
    const float* X  = (const float*)d_in[0];
    const float* y0 = (const float*)d_in[1];
    const float* W1 = (const float*)d_in[2];
    const float* b1 = (const float*)d_in[3];
    const float* W2 = (const float*)d_in[4];
    const float* b2 = (const float*)d_in[5];
    float* out = (float*)d_out;

    dim3 grid(B_TOT / 16);   // 1024 blocks x 4 waves = 4 waves/SIMD chip-wide
    dim3 block(64 * NW);
    narx_wave4<<<grid, block, 0, stream>>>(X, y0, W1, b1, W2, b2, out);
}

// Round 2
// 640.543 us; speedup vs baseline: 1.9485x; 1.9485x over previous
//
#include <hip/hip_runtime.h>

#define B_TOT 16384
#define T_STEPS 128
#define F_IN 29
#define K_HID 512
#define D_IN 32
#define NW 4        // waves per block (node dimension split 4 ways)
#define NTILE 8     // node tiles per wave = 512 / (16*NW)
#define XS 33       // sX row stride (floats): frag-read banks <=2-way aliased (free)

typedef __attribute__((ext_vector_type(8))) short short8;   // 8 bf16 (MFMA A/B frag)
typedef __attribute__((ext_vector_type(4))) float floatx4;  // MFMA C/D frag

__device__ __forceinline__ float fast_tanh(float x) {
    float e = __expf(2.0f * x);
    return 1.0f - 2.0f * __builtin_amdgcn_rcpf(e + 1.0f);
}
__device__ __forceinline__ short bf16_hi_bits(float x) {
    return (short)(__float_as_uint(x) >> 16);
}
__device__ __forceinline__ float bf16_hi_f(float x) {
    return __uint_as_float(__float_as_uint(x) & 0xffff0000u);
}

// 4 waves per block; each wave owns the SAME 16 batch rows but 1/4 of the 512
// hidden nodes (8 MFMA tiles, bf16x3). 1024 blocks x 4 waves = 16 waves/CU,
// so one wave's tanh/W2 VALU work hides under another wave's MFMA/stalls.
// REGISTER BUDGET (the R1 lesson): at 4 waves/SIMD the unified VGPR budget is
// 128/wave and the compiler splits arch/accum when AGPRs are used — forcing
// launch_bounds(...,4) gave 64 arch VGPRs and catastrophic spill (3.3 GB
// scratch fetch). So: bounds (256,2) = no forced cap, and the wlo fragments
// live in LDS (saves 32 arch VGPRs) so natural allocation lands <=128 and all
// 4 blocks/CU stay resident.
__global__ __launch_bounds__(256, 2)
void narx_wave4(const float* __restrict__ X,   // [B][T][29]
                const float* __restrict__ y0,  // [B][3]
                const float* __restrict__ W1,  // [32][512]
                const float* __restrict__ b1,  // [512]
                const float* __restrict__ W2,  // [512]
                const float* __restrict__ b2,  // [1]
                float* __restrict__ out)       // [B][T]
{
    __shared__ float sX[2][16 * XS];           // 4224 B
    __shared__ float pp[2][NW][16];            // 512 B: per-wave W2 partials
    __shared__ short8 sWlo[NW * NTILE * 64];   // 32 KiB: W1-low B-frags, per lane

    const int tid  = threadIdx.x;       // 0..255
    const int wv   = tid >> 6;          // wave id 0..3
    const int lane = tid & 63;
    const int q    = lane >> 4;         // 0..3
    const int m    = lane & 15;         // batch row (A/C) and node col (B)
    const size_t row0 = (size_t)blockIdx.x * 16;

    // ---- one-time: this wave's W1 B-fragments; hi in regs, lo in LDS ----
    // wave wv owns nodes [wv*128, wv*128+128); B[k][n]: n = lane&15, k = q*8+j
    short8 whi[NTILE];
    float b1v[NTILE], w2v[NTILE];
    #pragma unroll
    for (int nt = 0; nt < NTILE; ++nt) {
        int node = wv * (NTILE * 16) + nt * 16 + m;
        short8 lo;
        #pragma unroll
        for (int j = 0; j < 8; ++j) {
            int k = q * 8 + j;
            float v  = W1[k * K_HID + node];
            float hf = bf16_hi_f(v);
            whi[nt][j] = bf16_hi_bits(v);
            lo[j]      = bf16_hi_bits(v - hf);
        }
        sWlo[(wv * NTILE + nt) * 64 + lane] = lo;
        b1v[nt] = b1[node];
        w2v[nt] = W2[node];
    }
    const float b2v = b2[0];
    const short8* wloP = &sWlo[wv * NTILE * 64 + lane];

    // every lane tracks fb for its own row m (identical across waves)
    float fb0 = y0[(row0 + m) * 3 + 0];
    float fb1 = y0[(row0 + m) * 3 + 1];
    float fb2 = y0[(row0 + m) * 3 + 2];

    // ---- X staging: 464 floats/step spread over 256 threads (<=2 each) ----
    const float* Xblk = X + row0 * (T_STEPS * F_IN);
    const int f0 = tid;                    // always < 464
    const int f1 = tid + 256;
    const bool v1 = (f1 < 16 * F_IN);
    const int r0 = f0 / F_IN, c0 = f0 - r0 * F_IN;
    const int r1 = f1 / F_IN, c1 = f1 - r1 * F_IN;
    const int xo0 = r0 * (T_STEPS * F_IN) + c0;
    const int xo1 = r1 * (T_STEPS * F_IN) + c1;
    const int lo0 = r0 * XS + c0;
    const int lo1 = r1 * XS + c1;

    // stage X(0)
    float xp0 = Xblk[xo0];
    float xp1 = v1 ? Xblk[xo1] : 0.f;
    sX[0][lo0] = xp0;
    if (v1) sX[0][lo1] = xp1;

    float4 pv = make_float4(0.f, 0.f, 0.f, 0.f);

    for (int t = 0; t < T_STEPS; ++t) {
        const int cur = t & 1;
        __syncthreads();   // publishes: sX[cur]=X(t), pp[cur^1]=partials(t-1)
                           // (t=0: also covers sWlo + sX[0] prologue writes)

        // ---- combine pred(t-1) across waves; feedback shift; output ----
        if (t > 0) {
            const int pb = cur ^ 1;
            float fbn = pp[pb][0][m] + pp[pb][1][m]
                      + pp[pb][2][m] + pp[pb][3][m] + b2v;
            fb2 = fb1; fb1 = fb0; fb0 = fbn;
            if (wv == 0 && m < 4) {        // lane (q, m<4) owns row q*4+m
                const int ro = q * 4 + m;
                float po = pp[pb][0][ro] + pp[pb][1][ro]
                         + pp[pb][2][ro] + pp[pb][3][ro] + b2v;
                pv = make_float4(pv.y, pv.z, pv.w, po);
                if (((t - 1) & 3) == 3)
                    *(float4*)&out[(row0 + ro) * T_STEPS + (t - 4)] = pv;
            }
        }

        // ---- A-frag: LDS reads + fb inject + bf16 hi/lo split ----
        const float* sxm = &sX[cur][m * XS];
        short8 ahi, alo;
        #pragma unroll
        for (int j = 0; j < 8; ++j) {
            float xj = sxm[q * 8 + j];
            if (q == 3 && j == 5) xj = fb0;   // k = 29
            if (q == 3 && j == 6) xj = fb1;   // k = 30
            if (q == 3 && j == 7) xj = fb2;   // k = 31
            float hf = bf16_hi_f(xj);
            ahi[j] = bf16_hi_bits(xj);
            alo[j] = bf16_hi_bits(xj - hf);
        }

        // prefetch X(t+1) into registers (drained at the ds_write below)
        const int tn = (t + 1 < T_STEPS) ? (t + 1) : t;
        xp0 = Xblk[xo0 + tn * F_IN];
        if (v1) xp1 = Xblk[xo1 + tn * F_IN];

        // ---- 8 node tiles: bf16x3 MFMA + tanh + W2 partial ----
        float pa0 = 0.f, pa1 = 0.f, pa2 = 0.f, pa3 = 0.f;
        #pragma unroll
        for (int nt = 0; nt < NTILE; ++nt) {
            short8 wl = wloP[nt * 64];     // W1-low frag from LDS (wave-private)
            floatx4 c = {b1v[nt], b1v[nt], b1v[nt], b1v[nt]};
            c = __builtin_amdgcn_mfma_f32_16x16x32_bf16(ahi, whi[nt], c, 0, 0, 0);
            c = __builtin_amdgcn_mfma_f32_16x16x32_bf16(ahi, wl,      c, 0, 0, 0);
            c = __builtin_amdgcn_mfma_f32_16x16x32_bf16(alo, whi[nt], c, 0, 0, 0);
            // C/D: col(node) = lane&15, row(batch) = q*4 + reg
            pa0 = fmaf(fast_tanh(c[0]), w2v[nt], pa0);
            pa1 = fmaf(fast_tanh(c[1]), w2v[nt], pa1);
            pa2 = fmaf(fast_tanh(c[2]), w2v[nt], pa2);
            pa3 = fmaf(fast_tanh(c[3]), w2v[nt], pa3);
        }

        // ---- in-wave reduce over the 16 node cols (lane bits 0..3) ----
        #pragma unroll
        for (int mask = 1; mask <= 8; mask <<= 1) {
            pa0 += __shfl_xor(pa0, mask, 64);
            pa1 += __shfl_xor(pa1, mask, 64);
            pa2 += __shfl_xor(pa2, mask, 64);
            pa3 += __shfl_xor(pa3, mask, 64);
        }
        // pa[reg] = this wave's partial for row q*4+reg, replicated over m

        if (m == 0)
            *(float4*)&pp[cur][wv][q * 4] = make_float4(pa0, pa1, pa2, pa3);

        // ---- publish X(t+1) into the other buffer ----
        sX[cur ^ 1][lo0] = xp0;
        if (v1) sX[cur ^ 1][lo1] = xp1;
    }

    // ---- tail: combine pred(127), flush last output quad ----
    __syncthreads();
    if (wv == 0 && m < 4) {
        const int pb = (T_STEPS - 1) & 1;
        const int ro = q * 4 + m;
        float po = pp[pb][0][ro] + pp[pb][1][ro]
                 + pp[pb][2][ro] + pp[pb][3][ro] + b2v;
        pv = make_float4(pv.y, pv.z, pv.w, po);
        *(float4*)&out[(row0 + ro) * T_STEPS + (T_STEPS - 4)] = pv;
    }
}

extern "C" void kernel_launch(void* const* d_in, const int* in_sizes, int n_in,
                              void* d_out, int out_size, void* d_ws, size_t ws_size,
                              hipStream_t stream) {
    const float* X  = (const float*)d_in[0];
    const float* y0 = (const float*)d_in[1];
    const float* W1 = (const float*)d_in[2];
    const float* b1 = (const float*)d_in[3];
    const float* W2 = (const float*)d_in[4];
    const float* b2 = (const float*)d_in[5];
    float* out = (float*)d_out;

    dim3 grid(B_TOT / 16);   // 1024 blocks x 4 waves = 16 waves/CU chip-wide
    dim3 block(64 * NW);
    narx_wave4<<<grid, block, 0, stream>>>(X, y0, W1, b1, W2, b2, out);
}